// Round 10
// baseline (490.173 us; speedup 1.0000x reference)
//
#include <hip/hip_runtime.h>
#include <hip/hip_bf16.h>
#include <stdint.h>

typedef unsigned short u16;
typedef unsigned int u32;
typedef __attribute__((ext_vector_type(8))) short bf16x8;   // 8 bf16 = 4 VGPR
typedef __attribute__((ext_vector_type(4))) float f32x4;

// problem dims (fixed)
#define TT 2048
#define BB 2
#define HH 16
#define RR 8
#define SS 2048
#define MROWS 4096   // T*B

__device__ __forceinline__ float bf2f(u16 h){ union { u32 u; float f; } v; v.u = ((u32)h) << 16; return v.f; }
__device__ __forceinline__ u16 f2bf(float f){ union { float f; u32 u; } v; v.f = f; return (u16)((v.u + 0x7FFFu + ((v.u >> 16) & 1u)) >> 16); }
__device__ __forceinline__ void gl_lds16(const void* g, void* l){
  __builtin_amdgcn_global_load_lds((const __attribute__((address_space(1))) u32*)g,
                                   (__attribute__((address_space(3))) u32*)l, 16, 0, 0);
}

// ---------- f32 -> bf16 convert (optional scale) ----------
__global__ void k_cvt(const float* __restrict__ s, u16* __restrict__ d, int n, float scale){
  int i = blockIdx.x * blockDim.x + threadIdx.x;
  int st = gridDim.x * blockDim.x;
  for (; i < n; i += st) d[i] = f2bf(s[i] * scale);
}

// pack biases: bq*0.125 | bk | bv   (q-scaling folded into Wq/bq)
__global__ void k_bias(const float* __restrict__ bq, const float* __restrict__ bk,
                       const float* __restrict__ bv, float* __restrict__ bb){
  int i = blockIdx.x * blockDim.x + threadIdx.x;
  if (i < 1024){ bb[i] = bq[i] * 0.125f; bb[1024 + i] = bk[i]; bb[2048 + i] = bv[i]; }
}

// ---------- GEMM: C[Mx*] = A[MxKD] * Bt[NxKD]^T + bias; tile 128x128, BK=32 ----------
template<int KD, bool OBF>
__launch_bounds__(256, 2)
__global__ void k_gemm(const u16* __restrict__ A, const u16* __restrict__ Bt,
                       const float* __restrict__ bias, void* __restrict__ Cout, int ldc){
  __shared__ u16 As[128*32];
  __shared__ u16 Bs[128*32];
  const int tid = threadIdx.x, lane = tid & 63, wid = tid >> 6;
  const int mw = wid >> 1, nw = wid & 1;
  const int m0 = blockIdx.y * 128, n0 = blockIdx.x * 128;
  const f32x4 fzero = {0.f, 0.f, 0.f, 0.f};
  f32x4 acc[4][4];
  #pragma unroll
  for (int a = 0; a < 4; ++a)
    #pragma unroll
    for (int c = 0; c < 4; ++c) acc[a][c] = fzero;

  for (int k0 = 0; k0 < KD; k0 += 32){
    #pragma unroll
    for (int it = 0; it < 2; ++it){
      int c = it*256 + tid, r = c >> 2, sl = c & 3;
      gl_lds16(A + (size_t)(m0 + r)*KD + k0 + 8*(sl ^ ((r >> 1) & 3)), &As[c*8]);
    }
    #pragma unroll
    for (int it = 0; it < 2; ++it){
      int c = it*256 + tid, r = c >> 2, sl = c & 3;
      gl_lds16(Bt + (size_t)(n0 + r)*KD + k0 + 8*(sl ^ ((r >> 1) & 3)), &Bs[c*8]);
    }
    __syncthreads();
    bf16x8 af[4], bfr[4];
    #pragma unroll
    for (int mt = 0; mt < 4; ++mt){
      int r = mw*64 + mt*16 + (lane & 15);
      int pos = (lane >> 4) ^ ((r >> 1) & 3);
      af[mt] = *(const bf16x8*)&As[r*32 + pos*8];
    }
    #pragma unroll
    for (int nt = 0; nt < 4; ++nt){
      int r = nw*64 + nt*16 + (lane & 15);
      int pos = (lane >> 4) ^ ((r >> 1) & 3);
      bfr[nt] = *(const bf16x8*)&Bs[r*32 + pos*8];
    }
    #pragma unroll
    for (int mt = 0; mt < 4; ++mt)
      #pragma unroll
      for (int nt = 0; nt < 4; ++nt)
        acc[mt][nt] = __builtin_amdgcn_mfma_f32_16x16x32_bf16(af[mt], bfr[nt], acc[mt][nt], 0, 0, 0);
    __syncthreads();
  }
  #pragma unroll
  for (int nt = 0; nt < 4; ++nt){
    int col = n0 + nw*64 + nt*16 + (lane & 15);
    float bvv = bias[col];
    #pragma unroll
    for (int mt = 0; mt < 4; ++mt)
      #pragma unroll
      for (int j = 0; j < 4; ++j){
        int row = m0 + mw*64 + mt*16 + (lane >> 4)*4 + j;
        float v = acc[mt][nt][j] + bvv;
        if constexpr (OBF) ((u16*)Cout)[(size_t)row*ldc + col] = f2bf(v);
        else               ((float*)Cout)[(size_t)row*ldc + col] = v;
      }
  }
}

// ---------- transpose V block of qkv into rule-interleaved Vt2[b][d*8+r][s] ----------
__global__ void k_transpose(const u16* __restrict__ qkvb, u16* __restrict__ Vt2){
  __shared__ u16 tile[32][33];
  const int b = blockIdx.z;
  const int s0 = blockIdx.x * 32, n0 = blockIdx.y * 32;
  const int tx = threadIdx.x & 31, ty = threadIdx.x >> 5;  // 256 thr: 32x8
  for (int i = ty; i < 32; i += 8)
    tile[i][tx] = qkvb[(size_t)((s0 + i)*BB + b)*3072 + 2048 + n0 + tx];
  __syncthreads();
  for (int i = ty; i < 32; i += 8){
    int c = n0 + i;                       // original v-col = r*128 + d
    int nr = ((c & 127) << 3) | (c >> 7); // d*8 + r
    Vt2[(size_t)b*1024*SS + (size_t)nr*SS + s0 + tx] = tile[tx][i];
  }
}

// ---------- vw_aug[b][16][s]: rows 0..7 = sum_d v[b,r,s,d]*Wsc[64+d]; row 8 = 1; rest 0 ----
__global__ void k_vw2(const u16* __restrict__ qkvb, const float* __restrict__ Wsc,
                      u16* __restrict__ vwa){
  int idx = blockIdx.x * blockDim.x + threadIdx.x;   // over BB*16*SS = 65536
  if (idx >= BB*16*SS) return;
  int s = idx & (SS - 1);
  int r = (idx >> 11) & 15;
  int b = idx >> 15;
  float a;
  if (r < 8){
    const u16* vrow = qkvb + (size_t)(s*BB + b)*3072 + 2048 + r*128;
    a = 0.f;
    #pragma unroll 8
    for (int d = 0; d < 128; ++d) a += bf2f(vrow[d]) * Wsc[64 + d];
  } else if (r == 8) a = 1.0f;
  else a = 0.f;
  vwa[(size_t)(b*16 + r)*SS + s] = f2bf(a);
}

// ---------- k_attn2: single-pass p=exp(QK^T) -> probs (coalesced via LDS), ----------
// ---------- pw via vwa-MFMA (incl rowsum row), selection softmax -> selp     ----------
__launch_bounds__(512, 4)
__global__ void k_attn2(const u16* __restrict__ qkvb, const u16* __restrict__ vwa,
                        u16* __restrict__ probs, float* __restrict__ selp, int bh0){
  __shared__ u16 Qs[64*64];     // 8 KB (XOR r&7 swizzle)
  __shared__ u16 Ks[128*64];    // 16 KB
  __shared__ u16 P[64*136];     // 17.4 KB (+8 pad)
  __shared__ float pwL[8][16][16];  // 8 KB
  const int tid = threadIdx.x, lane = tid & 63, wid = tid >> 6;
  const int bhl = blockIdx.y;
  const int bh = bh0 + bhl;
  const int t0 = blockIdx.x * 64;
  const int b = bh >> 4, h = bh & 15;
  const u16* qbase = qkvb + b*3072 + h*64;
  const u16* kbase = qkvb + b*3072 + 1024 + h*64;
  const u16* vwbase = vwa + (size_t)b*16*SS;
  u16* pbase = probs + ((size_t)bhl*TT + t0)*SS;
  const f32x4 fzero = {0.f, 0.f, 0.f, 0.f};

  { // stage Q 64x64 once
    int c = tid, r = c >> 3, sl = c & 7;
    gl_lds16(qbase + (size_t)(t0 + r)*6144 + 8*(sl ^ (r & 7)), &Qs[c*8]);
  }
  __syncthreads();
  bf16x8 qf[4][2];
  #pragma unroll
  for (int mt = 0; mt < 4; ++mt)
    #pragma unroll
    for (int kk = 0; kk < 2; ++kk){
      int r = mt*16 + (lane & 15);
      int pos = (kk*4 + (lane >> 4)) ^ (r & 7);
      qf[mt][kk] = *(const bf16x8*)&Qs[r*64 + pos*8];
    }

  f32x4 pwacc = fzero;
  const int mtp = wid & 3, kks = (wid >> 2)*2;   // pw split: wave -> (mt, kk-pair)

  for (int s0 = 0; s0 < SS; s0 += 128){
    #pragma unroll
    for (int it = 0; it < 2; ++it){
      int c = it*512 + tid, r = c >> 3, sl = c & 7;
      gl_lds16(kbase + (size_t)(s0 + r)*6144 + 8*(sl ^ (r & 7)), &Ks[c*8]);
    }
    __syncthreads();   // K staged; prev-iter P reads (pw/copy) already drained at this barrier
    bf16x8 kf[2];
    #pragma unroll
    for (int kk = 0; kk < 2; ++kk){
      int r = wid*16 + (lane & 15);
      int pos = (kk*4 + (lane >> 4)) ^ (r & 7);
      kf[kk] = *(const bf16x8*)&Ks[r*64 + pos*8];
    }
    // swapped S' = mfma(K, Q): lane holds t = bt*16+(lane&15); s = wid*16+(lane>>4)*4+j
    #pragma unroll
    for (int bt = 0; bt < 4; ++bt){
      f32x4 sa = fzero;
      sa = __builtin_amdgcn_mfma_f32_16x16x32_bf16(kf[0], qf[bt][0], sa, 0, 0, 0);
      sa = __builtin_amdgcn_mfma_f32_16x16x32_bf16(kf[1], qf[bt][1], sa, 0, 0, 0);
      u32 w0 = (u32)f2bf(__expf(sa[0])) | ((u32)f2bf(__expf(sa[1])) << 16);
      u32 w1 = (u32)f2bf(__expf(sa[2])) | ((u32)f2bf(__expf(sa[3])) << 16);
      int t = bt*16 + (lane & 15);
      int sl = wid*16 + (lane >> 4)*4;
      uint2 pk; pk.x = w0; pk.y = w1;
      *(uint2*)&P[t*136 + sl] = pk;
    }
    __syncthreads();   // P complete
    bf16x8 vwf[2];
    #pragma unroll
    for (int kq = 0; kq < 2; ++kq)
      vwf[kq] = *(const bf16x8*)&vwbase[(size_t)(lane & 15)*SS + s0 + (kks + kq)*32 + (lane >> 4)*8];
    #pragma unroll
    for (int kq = 0; kq < 2; ++kq){
      int kk = kks + kq;
      bf16x8 pa = *(const bf16x8*)&P[(mtp*16 + (lane & 15))*136 + kk*32 + (lane >> 4)*8];
      pwacc = __builtin_amdgcn_mfma_f32_16x16x32_bf16(pa, vwf[kq], pwacc, 0, 0, 0);
    }
    // coalesced copy P tile (64x128) to global: 256B contiguous per row
    #pragma unroll
    for (int cc = 0; cc < 2; ++cc){
      int c = cc*512 + tid;          // 1024 chunks of 8 elems
      int row = c >> 4, col = c & 15;
      bf16x8 v = *(const bf16x8*)&P[row*136 + col*8];
      *(bf16x8*)&pbase[(size_t)row*SS + s0 + col*8] = v;
    }
  }

  // selection: combine pw halves, softmax over rules, selp = sel/rowsum
  #pragma unroll
  for (int j = 0; j < 4; ++j)
    pwL[wid][(lane >> 4)*4 + j][lane & 15] = pwacc[j];
  __syncthreads();
  if (tid < 64){
    int mt = tid >> 4, tr = tid & 15;
    float pw[9];
    #pragma unroll
    for (int r = 0; r < 9; ++r) pw[r] = pwL[mt][tr][r] + pwL[mt + 4][tr][r];
    float rs = pw[8];
    float inv = 1.0f / rs;
    float mx = -3.0e38f;
    #pragma unroll
    for (int r = 0; r < 8; ++r) mx = fmaxf(mx, pw[r]*inv);
    float e[8], ssum = 0.f;
    #pragma unroll
    for (int r = 0; r < 8; ++r){ e[r] = __expf(pw[r]*inv - mx); ssum += e[r]; }
    #pragma unroll
    for (int r = 0; r < 8; ++r)
      selp[((size_t)bh*TT + t0 + tid)*8 + r] = e[r] / (ssum * rs);
  }
}

// ---------- k_pv5: 256x128 block, 8 waves of 64x64, cross-unit register pipelining ----------
// ROUND-10 CHANGE: rounds 8-9 had reads and their consuming MFMAs in the SAME unit ->
// wall = LDS + MFMA (sum, 2561 cyc; MfmaUtil 45%). Now frags are register-double-buffered:
// unit q's MFMAs consume frags read during unit q-1; unit q's ds_reads fetch slot q+1
// (landed via vmcnt(3) at end of q-1, published by that barrier). Reads and MFMAs are
// independent -> wall -> max(MFMA 621, LDS ~850 cyc). Smaller wave tile (64x64) cuts
// acc to 64 regs so the double-buffered frags fit without spill (~170 total < 256).
// Ring: 4 slots x 24 KB (A 256x32 + B 128x32) = 96 KB. 3 gl_lds/thread/stage.
// Slot roles at unit q: q=consume(regs) | q+1=prefetch-read | q+2=landed | q+3=writing.
__launch_bounds__(512, 2)
__global__ void k_pv5(const u16* __restrict__ probs, const u16* __restrict__ Vt2,
                      const float* __restrict__ selp, u16* __restrict__ oattn,
                      int bh0, int G){
  __shared__ u16 L[4*12288];   // 4 ring slots x 24 KB
  const int tid = threadIdx.x, lane = tid & 63, wid = tid >> 6;
  const int mw = wid >> 1, nw = wid & 1;    // 4 M-waves x 2 N-waves
  int fid = blockIdx.x, bhl, xy;
  if (G >= 8){ bhl = (fid & 7) + 8*(fid >> 9); xy = (fid >> 3) & 63; }
  else       { bhl = fid >> 6;                 xy = fid & 63; }
  const int t0 = (xy >> 3) * 256;
  const int n0 = (xy & 7) * 128;
  const int bh = bh0 + bhl, b = bh >> 4, h = bh & 15;
  const u16* Abase = probs + ((size_t)bhl*TT + t0)*SS;
  const u16* Bbase = Vt2 + (size_t)b*1024*SS + (size_t)n0*SS;
  const f32x4 fzero = {0.f, 0.f, 0.f, 0.f};
  f32x4 acc[4][4];
  #pragma unroll
  for (int a = 0; a < 4; ++a)
    #pragma unroll
    for (int c = 0; c < 4; ++c) acc[a][c] = fzero;

  auto stage = [&](int q){
    u16* As = &L[(q & 3) * 12288];
    u16* Bs = As + 8192;
    #pragma unroll
    for (int i = 0; i < 2; ++i){   // A: 256 rows x 32 (2 chunks/thread)
      int ci = i*512 + tid, r = ci >> 2, sl = ci & 3;
      gl_lds16(Abase + (size_t)r*SS + q*32 + 8*(sl ^ ((r >> 1) & 3)), &As[ci*8]);
    }
    {                              // B: 128 rows x 32 (1 chunk/thread)
      int ci = tid, r = ci >> 2, sl = ci & 3;
      gl_lds16(Bbase + (size_t)r*SS + q*32 + 8*(sl ^ ((r >> 1) & 3)), &Bs[ci*8]);
    }
  };
  auto read_frags = [&](int q, bf16x8 (&af)[4], bf16x8 (&bfr)[4]){
    const u16* As = &L[(q & 3) * 12288];
    const u16* Bs = As + 8192;
    #pragma unroll
    for (int mf = 0; mf < 4; ++mf){
      int r = mw*64 + mf*16 + (lane & 15);
      int pos = (lane >> 4) ^ ((r >> 1) & 3);
      af[mf] = *(const bf16x8*)&As[r*32 + pos*8];
    }
    #pragma unroll
    for (int nf = 0; nf < 4; ++nf){
      int r = nw*64 + nf*16 + (lane & 15);
      int pos = (lane >> 4) ^ ((r >> 1) & 3);
      bfr[nf] = *(const bf16x8*)&Bs[r*32 + pos*8];
    }
  };
  auto mfma16 = [&](bf16x8 (&af)[4], bf16x8 (&bfr)[4]){
    __builtin_amdgcn_s_setprio(1);
    #pragma unroll
    for (int mf = 0; mf < 4; ++mf)
      #pragma unroll
      for (int nf = 0; nf < 4; ++nf)
        acc[mf][nf] = __builtin_amdgcn_mfma_f32_16x16x32_bf16(af[mf], bfr[nf], acc[mf][nf], 0, 0, 0);
    __builtin_amdgcn_s_setprio(0);
  };
  auto endwait = [&](int q){
    if (q <= 60) asm volatile("s_waitcnt vmcnt(3)" ::: "memory");  // stage q+2 landed; q+3 in flight
    else         asm volatile("s_waitcnt vmcnt(0)" ::: "memory");  // tail drain
    __builtin_amdgcn_s_barrier();                                  // publish slot q+2
    __builtin_amdgcn_sched_barrier(0);                             // pin later LDS ops below
  };

  bf16x8 afA[4], bfA[4], afB[4], bfB[4];
  stage(0); stage(1); stage(2);                      // 9 loads in flight
  asm volatile("s_waitcnt vmcnt(3)" ::: "memory");   // slots 0,1 landed; 2 in flight
  __builtin_amdgcn_s_barrier();
  __builtin_amdgcn_sched_barrier(0);
  read_frags(0, afA, bfA);

  for (int qq = 0; qq < 64; qq += 2){
    // unit qq: consume A-frags; prefetch slot qq+1 into B-frags
    if (qq + 3 < 64) stage(qq + 3);                  // writes slot (qq-1)&3: dead since last barrier
    read_frags(qq + 1, afB, bfB);                    // slot qq+1 published
    mfma16(afA, bfA);
    endwait(qq);
    // unit qq+1: consume B-frags; prefetch slot qq+2 into A-frags
    if (qq + 4 < 64) stage(qq + 4);
    if (qq + 2 < 64) read_frags(qq + 2, afA, bfA);
    mfma16(afB, bfB);
    endwait(qq + 1);
  }

  // register epilogue: col = n0 + nw*64 + nf*16 + c15; rule = c15&7; d = col>>3.
  const int c15 = lane & 15, g = lane >> 4, r8 = c15 & 7;
  float sel[4][4];
  #pragma unroll
  for (int mf = 0; mf < 4; ++mf)
    #pragma unroll
    for (int j = 0; j < 4; ++j){
      int trow = t0 + mw*64 + mf*16 + g*4 + j;
      sel[mf][j] = selp[((size_t)bh*TT + trow)*8 + r8];
    }
  #pragma unroll
  for (int mf = 0; mf < 4; ++mf)
    #pragma unroll
    for (int nf = 0; nf < 4; ++nf){
      float v0 = acc[mf][nf][0] * sel[mf][0];
      float v1 = acc[mf][nf][1] * sel[mf][1];
      float v2 = acc[mf][nf][2] * sel[mf][2];
      float v3 = acc[mf][nf][3] * sel[mf][3];
      #pragma unroll
      for (int mask = 1; mask < 8; mask <<= 1){
        v0 += __shfl_xor(v0, mask, 64);
        v1 += __shfl_xor(v1, mask, 64);
        v2 += __shfl_xor(v2, mask, 64);
        v3 += __shfl_xor(v3, mask, 64);
      }
      if (r8 == 0){
        int dglob = (n0 >> 3) + nw*8 + nf*2 + (c15 >> 3);
        int tb = t0 + mw*64 + mf*16 + g*4;
        u16* dst = oattn + (size_t)(tb*BB + b)*2048 + h*128 + dglob;
        dst[0*BB*2048] = f2bf(v0);
        dst[1*BB*2048] = f2bf(v1);
        dst[2*BB*2048] = f2bf(v2);
        dst[3*BB*2048] = f2bf(v3);
      }
    }
}

// ------------------------------------------------------------------
extern "C" void kernel_launch(void* const* d_in, const int* in_sizes, int n_in,
                              void* d_out, int out_size, void* d_ws, size_t ws_size,
                              hipStream_t stream){
  (void)in_sizes; (void)n_in;
  const float* query = (const float*)d_in[0];
  const float* Wq  = (const float*)d_in[1];
  const float* bq  = (const float*)d_in[2];
  const float* Wk  = (const float*)d_in[3];
  const float* bk  = (const float*)d_in[4];
  const float* Wv  = (const float*)d_in[5];
  const float* bv  = (const float*)d_in[6];
  // d_in[7] Wvq, d_in[8] bvq, d_in[10] bsc: provably unused (softmax_r shift-invariance)
  const float* Wsc = (const float*)d_in[9];
  const float* Wo  = (const float*)d_in[11];
  const float* bo  = (const float*)d_in[12];

  char* p = (char*)d_ws;
  auto carve = [&](size_t bytes) -> char* {
    char* r = p; p += (bytes + 255) & ~((size_t)255); return r;
  };
  u16*   Xb     = (u16*)  carve((size_t)MROWS*1024*2);     // query bf16          8.4 MB
  u16*   Wb     = (u16*)  carve((size_t)3072*1024*2);      // [Wq*.125|Wk|Wv]     6.3 MB
  u16*   Wob    = (u16*)  carve((size_t)1024*2048*2);      // Wo bf16             4.2 MB
  float* bb     = (float*)carve(3072*4);
  u16*   qkvb   = (u16*)  carve((size_t)MROWS*3072*2);     // [q|k|v] bf16       25.2 MB
  u16*   Vt2    = (u16*)  carve((size_t)BB*1024*SS*2);     // V^T rule-interleaved 8.4 MB
  u16*   vwa    = (u16*)  carve((size_t)BB*16*SS*2);       // vw_aug              0.13 MB
  u16*   oattn  = (u16*)  carve((size_t)MROWS*2048*2);     // attn out bf16      16.8 MB
  float* selp   = (float*)carve((size_t)32*TT*RR*4);       // sel/rowsum          2.1 MB
  size_t fixed = (size_t)(p - (char*)d_ws);
  int G = 32;                                               // bh per chunk (probs = G*8.4MB)
  while (G > 1 && fixed + ((size_t)G*TT*SS*2 + 256) > ws_size) G >>= 1;
  u16* probs;
  if (fixed + ((size_t)G*TT*SS*2 + 256) <= ws_size){
    probs = (u16*)carve((size_t)G*TT*SS*2);
  } else {
    // ws too small even for G=1: overlay probs on Xb (8.39 MB each; Xb is dead
    // after the qkv GEMM and is re-created by k_cvt on every graph replay)
    G = 1;
    probs = Xb;
  }

  k_cvt<<<1024, 256, 0, stream>>>(query, Xb, MROWS*1024, 1.0f);
  k_cvt<<<512, 256, 0, stream>>>(Wq, Wb, 1024*1024, 0.125f);
  k_cvt<<<512, 256, 0, stream>>>(Wk, Wb + 1024*1024, 1024*1024, 1.0f);
  k_cvt<<<512, 256, 0, stream>>>(Wv, Wb + 2*1024*1024, 1024*1024, 1.0f);
  k_cvt<<<1024, 256, 0, stream>>>(Wo, Wob, 1024*2048, 1.0f);
  k_bias<<<4, 256, 0, stream>>>(bq, bk, bv, bb);
  k_gemm<1024, true><<<dim3(24, 32), 256, 0, stream>>>(Xb, Wb, bb, qkvb, 3072);
  k_transpose<<<dim3(64, 32, 2), 256, 0, stream>>>(qkvb, Vt2);
  k_vw2<<<256, 256, 0, stream>>>(qkvb, Wsc, vwa);
  for (int bh0 = 0; bh0 < 32; bh0 += G){
    k_attn2<<<dim3(32, G), 512, 0, stream>>>(qkvb, vwa, probs, selp, bh0);
    k_pv5<<<G*64, 512, 0, stream>>>(probs, Vt2, selp, oattn, bh0, G);
  }
  k_gemm<2048, false><<<dim3(8, 32), 256, 0, stream>>>(oattn, Wob, bo, d_out, 1024);
}

// Round 11
// 442.451 us; speedup vs baseline: 1.1079x; 1.1079x over previous
//
#include <hip/hip_runtime.h>
#include <hip/hip_bf16.h>
#include <stdint.h>

typedef unsigned short u16;
typedef unsigned int u32;
typedef __attribute__((ext_vector_type(8))) short bf16x8;   // 8 bf16 = 4 VGPR
typedef __attribute__((ext_vector_type(4))) float f32x4;

// problem dims (fixed)
#define TT 2048
#define BB 2
#define HH 16
#define RR 8
#define SS 2048
#define MROWS 4096   // T*B

__device__ __forceinline__ float bf2f(u16 h){ union { u32 u; float f; } v; v.u = ((u32)h) << 16; return v.f; }
__device__ __forceinline__ u16 f2bf(float f){ union { float f; u32 u; } v; v.f = f; return (u16)((v.u + 0x7FFFu + ((v.u >> 16) & 1u)) >> 16); }
__device__ __forceinline__ void gl_lds16(const void* g, void* l){
  __builtin_amdgcn_global_load_lds((const __attribute__((address_space(1))) u32*)g,
                                   (__attribute__((address_space(3))) u32*)l, 16, 0, 0);
}

// ---------- f32 -> bf16 convert (optional scale) ----------
__global__ void k_cvt(const float* __restrict__ s, u16* __restrict__ d, int n, float scale){
  int i = blockIdx.x * blockDim.x + threadIdx.x;
  int st = gridDim.x * blockDim.x;
  for (; i < n; i += st) d[i] = f2bf(s[i] * scale);
}

// pack biases: bq*0.125 | bk | bv   (q-scaling folded into Wq/bq)
__global__ void k_bias(const float* __restrict__ bq, const float* __restrict__ bk,
                       const float* __restrict__ bv, float* __restrict__ bb){
  int i = blockIdx.x * blockDim.x + threadIdx.x;
  if (i < 1024){ bb[i] = bq[i] * 0.125f; bb[1024 + i] = bk[i]; bb[2048 + i] = bv[i]; }
}

// ---------- GEMM: C[Mx*] = A[MxKD] * Bt[NxKD]^T + bias; tile 128x128, BK=32 ----------
template<int KD, bool OBF>
__launch_bounds__(256, 2)
__global__ void k_gemm(const u16* __restrict__ A, const u16* __restrict__ Bt,
                       const float* __restrict__ bias, void* __restrict__ Cout, int ldc){
  __shared__ u16 As[128*32];
  __shared__ u16 Bs[128*32];
  const int tid = threadIdx.x, lane = tid & 63, wid = tid >> 6;
  const int mw = wid >> 1, nw = wid & 1;
  const int m0 = blockIdx.y * 128, n0 = blockIdx.x * 128;
  const f32x4 fzero = {0.f, 0.f, 0.f, 0.f};
  f32x4 acc[4][4];
  #pragma unroll
  for (int a = 0; a < 4; ++a)
    #pragma unroll
    for (int c = 0; c < 4; ++c) acc[a][c] = fzero;

  for (int k0 = 0; k0 < KD; k0 += 32){
    #pragma unroll
    for (int it = 0; it < 2; ++it){
      int c = it*256 + tid, r = c >> 2, sl = c & 3;
      gl_lds16(A + (size_t)(m0 + r)*KD + k0 + 8*(sl ^ ((r >> 1) & 3)), &As[c*8]);
    }
    #pragma unroll
    for (int it = 0; it < 2; ++it){
      int c = it*256 + tid, r = c >> 2, sl = c & 3;
      gl_lds16(Bt + (size_t)(n0 + r)*KD + k0 + 8*(sl ^ ((r >> 1) & 3)), &Bs[c*8]);
    }
    __syncthreads();
    bf16x8 af[4], bfr[4];
    #pragma unroll
    for (int mt = 0; mt < 4; ++mt){
      int r = mw*64 + mt*16 + (lane & 15);
      int pos = (lane >> 4) ^ ((r >> 1) & 3);
      af[mt] = *(const bf16x8*)&As[r*32 + pos*8];
    }
    #pragma unroll
    for (int nt = 0; nt < 4; ++nt){
      int r = nw*64 + nt*16 + (lane & 15);
      int pos = (lane >> 4) ^ ((r >> 1) & 3);
      bfr[nt] = *(const bf16x8*)&Bs[r*32 + pos*8];
    }
    #pragma unroll
    for (int mt = 0; mt < 4; ++mt)
      #pragma unroll
      for (int nt = 0; nt < 4; ++nt)
        acc[mt][nt] = __builtin_amdgcn_mfma_f32_16x16x32_bf16(af[mt], bfr[nt], acc[mt][nt], 0, 0, 0);
    __syncthreads();
  }
  #pragma unroll
  for (int nt = 0; nt < 4; ++nt){
    int col = n0 + nw*64 + nt*16 + (lane & 15);
    float bvv = bias[col];
    #pragma unroll
    for (int mt = 0; mt < 4; ++mt)
      #pragma unroll
      for (int j = 0; j < 4; ++j){
        int row = m0 + mw*64 + mt*16 + (lane >> 4)*4 + j;
        float v = acc[mt][nt][j] + bvv;
        if constexpr (OBF) ((u16*)Cout)[(size_t)row*ldc + col] = f2bf(v);
        else               ((float*)Cout)[(size_t)row*ldc + col] = v;
      }
  }
}

// ---------- transpose V block of qkv into rule-interleaved Vt2[b][d*8+r][s] ----------
__global__ void k_transpose(const u16* __restrict__ qkvb, u16* __restrict__ Vt2){
  __shared__ u16 tile[32][33];
  const int b = blockIdx.z;
  const int s0 = blockIdx.x * 32, n0 = blockIdx.y * 32;
  const int tx = threadIdx.x & 31, ty = threadIdx.x >> 5;  // 256 thr: 32x8
  for (int i = ty; i < 32; i += 8)
    tile[i][tx] = qkvb[(size_t)((s0 + i)*BB + b)*3072 + 2048 + n0 + tx];
  __syncthreads();
  for (int i = ty; i < 32; i += 8){
    int c = n0 + i;                       // original v-col = r*128 + d
    int nr = ((c & 127) << 3) | (c >> 7); // d*8 + r
    Vt2[(size_t)b*1024*SS + (size_t)nr*SS + s0 + tx] = tile[tx][i];
  }
}

// ---------- vw_aug[b][16][s]: rows 0..7 = sum_d v[b,r,s,d]*Wsc[64+d]; row 8 = 1; rest 0 ----
__global__ void k_vw2(const u16* __restrict__ qkvb, const float* __restrict__ Wsc,
                      u16* __restrict__ vwa){
  int idx = blockIdx.x * blockDim.x + threadIdx.x;   // over BB*16*SS = 65536
  if (idx >= BB*16*SS) return;
  int s = idx & (SS - 1);
  int r = (idx >> 11) & 15;
  int b = idx >> 15;
  float a;
  if (r < 8){
    const u16* vrow = qkvb + (size_t)(s*BB + b)*3072 + 2048 + r*128;
    a = 0.f;
    #pragma unroll 8
    for (int d = 0; d < 128; ++d) a += bf2f(vrow[d]) * Wsc[64 + d];
  } else if (r == 8) a = 1.0f;
  else a = 0.f;
  vwa[(size_t)(b*16 + r)*SS + s] = f2bf(a);
}

// ---------- k_attn2: single-pass p=exp(QK^T) -> probs (coalesced via LDS), ----------
// ---------- pw via vwa-MFMA (incl rowsum row), selection softmax -> selp     ----------
__launch_bounds__(512, 4)
__global__ void k_attn2(const u16* __restrict__ qkvb, const u16* __restrict__ vwa,
                        u16* __restrict__ probs, float* __restrict__ selp, int bh0){
  __shared__ u16 Qs[64*64];     // 8 KB (XOR r&7 swizzle)
  __shared__ u16 Ks[128*64];    // 16 KB
  __shared__ u16 P[64*136];     // 17.4 KB (+8 pad)
  __shared__ float pwL[8][16][16];  // 8 KB
  const int tid = threadIdx.x, lane = tid & 63, wid = tid >> 6;
  const int bhl = blockIdx.y;
  const int bh = bh0 + bhl;
  const int t0 = blockIdx.x * 64;
  const int b = bh >> 4, h = bh & 15;
  const u16* qbase = qkvb + b*3072 + h*64;
  const u16* kbase = qkvb + b*3072 + 1024 + h*64;
  const u16* vwbase = vwa + (size_t)b*16*SS;
  u16* pbase = probs + ((size_t)bhl*TT + t0)*SS;
  const f32x4 fzero = {0.f, 0.f, 0.f, 0.f};

  { // stage Q 64x64 once
    int c = tid, r = c >> 3, sl = c & 7;
    gl_lds16(qbase + (size_t)(t0 + r)*6144 + 8*(sl ^ (r & 7)), &Qs[c*8]);
  }
  __syncthreads();
  bf16x8 qf[4][2];
  #pragma unroll
  for (int mt = 0; mt < 4; ++mt)
    #pragma unroll
    for (int kk = 0; kk < 2; ++kk){
      int r = mt*16 + (lane & 15);
      int pos = (kk*4 + (lane >> 4)) ^ (r & 7);
      qf[mt][kk] = *(const bf16x8*)&Qs[r*64 + pos*8];
    }

  f32x4 pwacc = fzero;
  const int mtp = wid & 3, kks = (wid >> 2)*2;   // pw split: wave -> (mt, kk-pair)

  for (int s0 = 0; s0 < SS; s0 += 128){
    #pragma unroll
    for (int it = 0; it < 2; ++it){
      int c = it*512 + tid, r = c >> 3, sl = c & 7;
      gl_lds16(kbase + (size_t)(s0 + r)*6144 + 8*(sl ^ (r & 7)), &Ks[c*8]);
    }
    __syncthreads();   // K staged; prev-iter P reads (pw/copy) already drained at this barrier
    bf16x8 kf[2];
    #pragma unroll
    for (int kk = 0; kk < 2; ++kk){
      int r = wid*16 + (lane & 15);
      int pos = (kk*4 + (lane >> 4)) ^ (r & 7);
      kf[kk] = *(const bf16x8*)&Ks[r*64 + pos*8];
    }
    // swapped S' = mfma(K, Q): lane holds t = bt*16+(lane&15); s = wid*16+(lane>>4)*4+j
    #pragma unroll
    for (int bt = 0; bt < 4; ++bt){
      f32x4 sa = fzero;
      sa = __builtin_amdgcn_mfma_f32_16x16x32_bf16(kf[0], qf[bt][0], sa, 0, 0, 0);
      sa = __builtin_amdgcn_mfma_f32_16x16x32_bf16(kf[1], qf[bt][1], sa, 0, 0, 0);
      u32 w0 = (u32)f2bf(__expf(sa[0])) | ((u32)f2bf(__expf(sa[1])) << 16);
      u32 w1 = (u32)f2bf(__expf(sa[2])) | ((u32)f2bf(__expf(sa[3])) << 16);
      int t = bt*16 + (lane & 15);
      int sl = wid*16 + (lane >> 4)*4;
      uint2 pk; pk.x = w0; pk.y = w1;
      *(uint2*)&P[t*136 + sl] = pk;
    }
    __syncthreads();   // P complete
    bf16x8 vwf[2];
    #pragma unroll
    for (int kq = 0; kq < 2; ++kq)
      vwf[kq] = *(const bf16x8*)&vwbase[(size_t)(lane & 15)*SS + s0 + (kks + kq)*32 + (lane >> 4)*8];
    #pragma unroll
    for (int kq = 0; kq < 2; ++kq){
      int kk = kks + kq;
      bf16x8 pa = *(const bf16x8*)&P[(mtp*16 + (lane & 15))*136 + kk*32 + (lane >> 4)*8];
      pwacc = __builtin_amdgcn_mfma_f32_16x16x32_bf16(pa, vwf[kq], pwacc, 0, 0, 0);
    }
    // coalesced copy P tile (64x128) to global: 256B contiguous per row
    #pragma unroll
    for (int cc = 0; cc < 2; ++cc){
      int c = cc*512 + tid;          // 1024 chunks of 8 elems
      int row = c >> 4, col = c & 15;
      bf16x8 v = *(const bf16x8*)&P[row*136 + col*8];
      *(bf16x8*)&pbase[(size_t)row*SS + s0 + col*8] = v;
    }
  }

  // selection: combine pw halves, softmax over rules, selp = sel/rowsum
  #pragma unroll
  for (int j = 0; j < 4; ++j)
    pwL[wid][(lane >> 4)*4 + j][lane & 15] = pwacc[j];
  __syncthreads();
  if (tid < 64){
    int mt = tid >> 4, tr = tid & 15;
    float pw[9];
    #pragma unroll
    for (int r = 0; r < 9; ++r) pw[r] = pwL[mt][tr][r] + pwL[mt + 4][tr][r];
    float rs = pw[8];
    float inv = 1.0f / rs;
    float mx = -3.0e38f;
    #pragma unroll
    for (int r = 0; r < 8; ++r) mx = fmaxf(mx, pw[r]*inv);
    float e[8], ssum = 0.f;
    #pragma unroll
    for (int r = 0; r < 8; ++r){ e[r] = __expf(pw[r]*inv - mx); ssum += e[r]; }
    #pragma unroll
    for (int r = 0; r < 8; ++r)
      selp[((size_t)bh*TT + t0 + tid)*8 + r] = e[r] / (ssum * rs);
  }
}

// ---------- k_pv4: 256x256-tile pipelined PV (round-9 ring/vmcnt, ROUND-11 body reorder) ----
// ROUND-10 LESSON: 256x128 tile + reg-dbuf regressed (LDS-bytes/MFMA 384->512 B, FETCH +33%).
// Reverted to the 256x256 geometry (1007 TF). ROUND-11: dependency-ordered unit body.
// Round-9 read all 12 frags then MFMA'd -> first MFMA needed read #9 -> ~full LDS drain,
// pipes serialized (wall = MFMA 1242 + DS ~1300 cyc). Now: bfr[0..3]+af[0] (5 reads), then
// per-mf groups {read af[mf+1]; 4 MFMA on af[mf]} -> first MFMA after 5 reads, later af
// reads hide under MFMA groups via the compiler's fine-grained lgkmcnt. Sync structure,
// ring slots, and vmcnt bookkeeping are byte-identical to round 9 (no new race surface).
__launch_bounds__(512, 2)
__global__ void k_pv4(const u16* __restrict__ probs, const u16* __restrict__ Vt2,
                      const float* __restrict__ selp, u16* __restrict__ oattn,
                      int bh0, int G){
  __shared__ u16 L[4*16384];   // 4 slots x 32 KB
  const int tid = threadIdx.x, lane = tid & 63, wid = tid >> 6;
  const int mw = wid & 1, nw2 = wid >> 1;   // 2 M-waves x 4 N-waves
  int fid = blockIdx.x, bhl, xy;
  if (G >= 8){ bhl = (fid & 7) + 8*(fid >> 8); xy = (fid >> 3) & 31; }
  else       { bhl = fid >> 5;                 xy = fid & 31; }
  const int t0 = (xy >> 2) * 256;
  const int n0 = (xy & 3) * 256;
  const int bh = bh0 + bhl, b = bh >> 4, h = bh & 15;
  const u16* Abase = probs + ((size_t)bhl*TT + t0)*SS;
  const u16* Bbase = Vt2 + (size_t)b*1024*SS + (size_t)n0*SS;
  const f32x4 fzero = {0.f, 0.f, 0.f, 0.f};
  f32x4 acc[8][4];
  #pragma unroll
  for (int a = 0; a < 8; ++a)
    #pragma unroll
    for (int c = 0; c < 4; ++c) acc[a][c] = fzero;

  auto stage = [&](int q){
    u16* As = &L[(q & 3) * 16384];
    u16* Bs = As + 8192;
    #pragma unroll
    for (int i = 0; i < 2; ++i){   // A: 256 rows x 32, 1024 chunks (2/thread)
      int ci = i*512 + tid, r = ci >> 2, sl = ci & 3;
      gl_lds16(Abase + (size_t)r*SS + q*32 + 8*(sl ^ ((r >> 1) & 3)), &As[ci*8]);
    }
    #pragma unroll
    for (int i = 0; i < 2; ++i){   // B: 256 rows x 32
      int ci = i*512 + tid, r = ci >> 2, sl = ci & 3;
      gl_lds16(Bbase + (size_t)r*SS + q*32 + 8*(sl ^ ((r >> 1) & 3)), &Bs[ci*8]);
    }
  };

  stage(0); stage(1); stage(2);                       // 12 loads in flight
  asm volatile("s_waitcnt vmcnt(8)" ::: "memory");    // unit 0 landed (own wave's writes)
  __builtin_amdgcn_s_barrier();                       // all waves' unit-0 writes visible
  __builtin_amdgcn_sched_barrier(0);                  // pin unit-0 ds_reads below the sync

  for (int q = 0; q < 64; ++q){
    const u16* As = &L[(q & 3) * 16384];
    const u16* Bs = As + 8192;
    bf16x8 af[8], bfr[4];
    // dependency-first reads: all B frags + af[0] (the first MFMA's operands)
    #pragma unroll
    for (int nf = 0; nf < 4; ++nf){
      int r = nw2*64 + nf*16 + (lane & 15);
      int pos = (lane >> 4) ^ ((r >> 1) & 3);
      bfr[nf] = *(const bf16x8*)&Bs[r*32 + pos*8];
    }
    {
      int r = mw*128 + (lane & 15);
      int pos = (lane >> 4) ^ ((r >> 1) & 3);
      af[0] = *(const bf16x8*)&As[r*32 + pos*8];
    }
    if (q + 3 < 64) stage(q + 3);                     // targets slot (q-1)&3: dead since last barrier
    __builtin_amdgcn_s_setprio(1);
    #pragma unroll
    for (int mf = 0; mf < 8; ++mf){
      if (mf < 7){                                    // prefetch next af under this group's MFMAs
        int r = mw*128 + (mf + 1)*16 + (lane & 15);
        int pos = (lane >> 4) ^ ((r >> 1) & 3);
        af[mf + 1] = *(const bf16x8*)&As[r*32 + pos*8];
      }
      #pragma unroll
      for (int nf = 0; nf < 4; ++nf)
        acc[mf][nf] = __builtin_amdgcn_mfma_f32_16x16x32_bf16(af[mf], bfr[nf], acc[mf][nf], 0, 0, 0);
    }
    __builtin_amdgcn_s_setprio(0);
    // end of unit: counted wait (units q+2,q+3 stay in flight -- never drains), barrier
    if (q < 61)       asm volatile("s_waitcnt vmcnt(8)" ::: "memory");
    else if (q == 61) asm volatile("s_waitcnt vmcnt(4)" ::: "memory");
    else              asm volatile("s_waitcnt vmcnt(0)" ::: "memory");
    __builtin_amdgcn_s_barrier();
    __builtin_amdgcn_sched_barrier(0);                // next unit's ds_reads stay below
  }

  // register epilogue: col = n0 + nw2*64 + nf*16 + c15; rule = c15&7; d = col>>3.
  const int c15 = lane & 15, g = lane >> 4, r8 = c15 & 7;
  float sel[8][4];
  #pragma unroll
  for (int mf = 0; mf < 8; ++mf)
    #pragma unroll
    for (int j = 0; j < 4; ++j){
      int trow = t0 + mw*128 + mf*16 + g*4 + j;
      sel[mf][j] = selp[((size_t)bh*TT + trow)*8 + r8];
    }
  #pragma unroll
  for (int mf = 0; mf < 8; ++mf)
    #pragma unroll
    for (int nf = 0; nf < 4; ++nf){
      float v0 = acc[mf][nf][0] * sel[mf][0];
      float v1 = acc[mf][nf][1] * sel[mf][1];
      float v2 = acc[mf][nf][2] * sel[mf][2];
      float v3 = acc[mf][nf][3] * sel[mf][3];
      #pragma unroll
      for (int mask = 1; mask < 8; mask <<= 1){
        v0 += __shfl_xor(v0, mask, 64);
        v1 += __shfl_xor(v1, mask, 64);
        v2 += __shfl_xor(v2, mask, 64);
        v3 += __shfl_xor(v3, mask, 64);
      }
      if (r8 == 0){
        int dglob = (n0 >> 3) + nw2*8 + nf*2 + (c15 >> 3);
        int tb = t0 + mw*128 + mf*16 + g*4;
        u16* dst = oattn + (size_t)(tb*BB + b)*2048 + h*128 + dglob;
        dst[0*BB*2048] = f2bf(v0);
        dst[1*BB*2048] = f2bf(v1);
        dst[2*BB*2048] = f2bf(v2);
        dst[3*BB*2048] = f2bf(v3);
      }
    }
}

// ------------------------------------------------------------------
extern "C" void kernel_launch(void* const* d_in, const int* in_sizes, int n_in,
                              void* d_out, int out_size, void* d_ws, size_t ws_size,
                              hipStream_t stream){
  (void)in_sizes; (void)n_in;
  const float* query = (const float*)d_in[0];
  const float* Wq  = (const float*)d_in[1];
  const float* bq  = (const float*)d_in[2];
  const float* Wk  = (const float*)d_in[3];
  const float* bk  = (const float*)d_in[4];
  const float* Wv  = (const float*)d_in[5];
  const float* bv  = (const float*)d_in[6];
  // d_in[7] Wvq, d_in[8] bvq, d_in[10] bsc: provably unused (softmax_r shift-invariance)
  const float* Wsc = (const float*)d_in[9];
  const float* Wo  = (const float*)d_in[11];
  const float* bo  = (const float*)d_in[12];

  char* p = (char*)d_ws;
  auto carve = [&](size_t bytes) -> char* {
    char* r = p; p += (bytes + 255) & ~((size_t)255); return r;
  };
  u16*   Xb     = (u16*)  carve((size_t)MROWS*1024*2);     // query bf16          8.4 MB
  u16*   Wb     = (u16*)  carve((size_t)3072*1024*2);      // [Wq*.125|Wk|Wv]     6.3 MB
  u16*   Wob    = (u16*)  carve((size_t)1024*2048*2);      // Wo bf16             4.2 MB
  float* bb     = (float*)carve(3072*4);
  u16*   qkvb   = (u16*)  carve((size_t)MROWS*3072*2);     // [q|k|v] bf16       25.2 MB
  u16*   Vt2    = (u16*)  carve((size_t)BB*1024*SS*2);     // V^T rule-interleaved 8.4 MB
  u16*   vwa    = (u16*)  carve((size_t)BB*16*SS*2);       // vw_aug              0.13 MB
  u16*   oattn  = (u16*)  carve((size_t)MROWS*2048*2);     // attn out bf16      16.8 MB
  float* selp   = (float*)carve((size_t)32*TT*RR*4);       // sel/rowsum          2.1 MB
  size_t fixed = (size_t)(p - (char*)d_ws);
  int G = 32;                                               // bh per chunk (probs = G*8.4MB)
  while (G > 1 && fixed + ((size_t)G*TT*SS*2 + 256) > ws_size) G >>= 1;
  u16* probs;
  if (fixed + ((size_t)G*TT*SS*2 + 256) <= ws_size){
    probs = (u16*)carve((size_t)G*TT*SS*2);
  } else {
    // ws too small even for G=1: overlay probs on Xb (8.39 MB each; Xb is dead
    // after the qkv GEMM and is re-created by k_cvt on every graph replay)
    G = 1;
    probs = Xb;
  }

  k_cvt<<<1024, 256, 0, stream>>>(query, Xb, MROWS*1024, 1.0f);
  k_cvt<<<512, 256, 0, stream>>>(Wq, Wb, 1024*1024, 0.125f);
  k_cvt<<<512, 256, 0, stream>>>(Wk, Wb + 1024*1024, 1024*1024, 1.0f);
  k_cvt<<<512, 256, 0, stream>>>(Wv, Wb + 2*1024*1024, 1024*1024, 1.0f);
  k_cvt<<<1024, 256, 0, stream>>>(Wo, Wob, 1024*2048, 1.0f);
  k_bias<<<4, 256, 0, stream>>>(bq, bk, bv, bb);
  k_gemm<1024, true><<<dim3(24, 32), 256, 0, stream>>>(Xb, Wb, bb, qkvb, 3072);
  k_transpose<<<dim3(64, 32, 2), 256, 0, stream>>>(qkvb, Vt2);
  k_vw2<<<256, 256, 0, stream>>>(qkvb, Wsc, vwa);
  for (int bh0 = 0; bh0 < 32; bh0 += G){
    k_attn2<<<dim3(32, G), 512, 0, stream>>>(qkvb, vwa, probs, selp, bh0);
    k_pv4<<<G*32, 512, 0, stream>>>(probs, Vt2, selp, oattn, bh0, G);
  }
  k_gemm<2048, false><<<dim3(8, 32), 256, 0, stream>>>(oattn, Wob, bo, d_out, 1024);
}

// Round 12
// 431.664 us; speedup vs baseline: 1.1355x; 1.0250x over previous
//
#include <hip/hip_runtime.h>
#include <hip/hip_bf16.h>
#include <stdint.h>

typedef unsigned short u16;
typedef unsigned int u32;
typedef __attribute__((ext_vector_type(8))) short bf16x8;   // 8 bf16 = 4 VGPR
typedef __attribute__((ext_vector_type(4))) float f32x4;

// problem dims (fixed)
#define TT 2048
#define BB 2
#define HH 16
#define RR 8
#define SS 2048
#define MROWS 4096   // T*B

__device__ __forceinline__ float bf2f(u16 h){ union { u32 u; float f; } v; v.u = ((u32)h) << 16; return v.f; }
__device__ __forceinline__ u16 f2bf(float f){ union { float f; u32 u; } v; v.f = f; return (u16)((v.u + 0x7FFFu + ((v.u >> 16) & 1u)) >> 16); }
__device__ __forceinline__ void gl_lds16(const void* g, void* l){
  __builtin_amdgcn_global_load_lds((const __attribute__((address_space(1))) u32*)g,
                                   (__attribute__((address_space(3))) u32*)l, 16, 0, 0);
}

// ---------- f32 -> bf16 convert (optional scale) ----------
__global__ void k_cvt(const float* __restrict__ s, u16* __restrict__ d, int n, float scale){
  int i = blockIdx.x * blockDim.x + threadIdx.x;
  int st = gridDim.x * blockDim.x;
  for (; i < n; i += st) d[i] = f2bf(s[i] * scale);
}

// pack biases: bq*0.125 | bk | bv   (q-scaling folded into Wq/bq)
__global__ void k_bias(const float* __restrict__ bq, const float* __restrict__ bk,
                       const float* __restrict__ bv, float* __restrict__ bb){
  int i = blockIdx.x * blockDim.x + threadIdx.x;
  if (i < 1024){ bb[i] = bq[i] * 0.125f; bb[1024 + i] = bk[i]; bb[2048 + i] = bv[i]; }
}

// ---------- GEMM: C[Mx*] = A[MxKD] * Bt[NxKD]^T + bias; tile 128x128, BK=32 ----------
template<int KD, bool OBF>
__launch_bounds__(256, 2)
__global__ void k_gemm(const u16* __restrict__ A, const u16* __restrict__ Bt,
                       const float* __restrict__ bias, void* __restrict__ Cout, int ldc){
  __shared__ u16 As[128*32];
  __shared__ u16 Bs[128*32];
  const int tid = threadIdx.x, lane = tid & 63, wid = tid >> 6;
  const int mw = wid >> 1, nw = wid & 1;
  const int m0 = blockIdx.y * 128, n0 = blockIdx.x * 128;
  const f32x4 fzero = {0.f, 0.f, 0.f, 0.f};
  f32x4 acc[4][4];
  #pragma unroll
  for (int a = 0; a < 4; ++a)
    #pragma unroll
    for (int c = 0; c < 4; ++c) acc[a][c] = fzero;

  for (int k0 = 0; k0 < KD; k0 += 32){
    #pragma unroll
    for (int it = 0; it < 2; ++it){
      int c = it*256 + tid, r = c >> 2, sl = c & 3;
      gl_lds16(A + (size_t)(m0 + r)*KD + k0 + 8*(sl ^ ((r >> 1) & 3)), &As[c*8]);
    }
    #pragma unroll
    for (int it = 0; it < 2; ++it){
      int c = it*256 + tid, r = c >> 2, sl = c & 3;
      gl_lds16(Bt + (size_t)(n0 + r)*KD + k0 + 8*(sl ^ ((r >> 1) & 3)), &Bs[c*8]);
    }
    __syncthreads();
    bf16x8 af[4], bfr[4];
    #pragma unroll
    for (int mt = 0; mt < 4; ++mt){
      int r = mw*64 + mt*16 + (lane & 15);
      int pos = (lane >> 4) ^ ((r >> 1) & 3);
      af[mt] = *(const bf16x8*)&As[r*32 + pos*8];
    }
    #pragma unroll
    for (int nt = 0; nt < 4; ++nt){
      int r = nw*64 + nt*16 + (lane & 15);
      int pos = (lane >> 4) ^ ((r >> 1) & 3);
      bfr[nt] = *(const bf16x8*)&Bs[r*32 + pos*8];
    }
    #pragma unroll
    for (int mt = 0; mt < 4; ++mt)
      #pragma unroll
      for (int nt = 0; nt < 4; ++nt)
        acc[mt][nt] = __builtin_amdgcn_mfma_f32_16x16x32_bf16(af[mt], bfr[nt], acc[mt][nt], 0, 0, 0);
    __syncthreads();
  }
  #pragma unroll
  for (int nt = 0; nt < 4; ++nt){
    int col = n0 + nw*64 + nt*16 + (lane & 15);
    float bvv = bias[col];
    #pragma unroll
    for (int mt = 0; mt < 4; ++mt)
      #pragma unroll
      for (int j = 0; j < 4; ++j){
        int row = m0 + mw*64 + mt*16 + (lane >> 4)*4 + j;
        float v = acc[mt][nt][j] + bvv;
        if constexpr (OBF) ((u16*)Cout)[(size_t)row*ldc + col] = f2bf(v);
        else               ((float*)Cout)[(size_t)row*ldc + col] = v;
      }
  }
}

// ---------- transpose V block of qkv into rule-interleaved Vt2[b][d*8+r][s] ----------
__global__ void k_transpose(const u16* __restrict__ qkvb, u16* __restrict__ Vt2){
  __shared__ u16 tile[32][33];
  const int b = blockIdx.z;
  const int s0 = blockIdx.x * 32, n0 = blockIdx.y * 32;
  const int tx = threadIdx.x & 31, ty = threadIdx.x >> 5;  // 256 thr: 32x8
  for (int i = ty; i < 32; i += 8)
    tile[i][tx] = qkvb[(size_t)((s0 + i)*BB + b)*3072 + 2048 + n0 + tx];
  __syncthreads();
  for (int i = ty; i < 32; i += 8){
    int c = n0 + i;                       // original v-col = r*128 + d
    int nr = ((c & 127) << 3) | (c >> 7); // d*8 + r
    Vt2[(size_t)b*1024*SS + (size_t)nr*SS + s0 + tx] = tile[tx][i];
  }
}

// ---------- vw_aug[b][16][s]: rows 0..7 = sum_d v[b,r,s,d]*Wsc[64+d]; row 8 = 1; rest 0 ----
__global__ void k_vw2(const u16* __restrict__ qkvb, const float* __restrict__ Wsc,
                      u16* __restrict__ vwa){
  int idx = blockIdx.x * blockDim.x + threadIdx.x;   // over BB*16*SS = 65536
  if (idx >= BB*16*SS) return;
  int s = idx & (SS - 1);
  int r = (idx >> 11) & 15;
  int b = idx >> 15;
  float a;
  if (r < 8){
    const u16* vrow = qkvb + (size_t)(s*BB + b)*3072 + 2048 + r*128;
    a = 0.f;
    #pragma unroll 8
    for (int d = 0; d < 128; ++d) a += bf2f(vrow[d]) * Wsc[64 + d];
  } else if (r == 8) a = 1.0f;
  else a = 0.f;
  vwa[(size_t)(b*16 + r)*SS + s] = f2bf(a);
}

// ---------- k_attn2: single-pass p=exp(QK^T) -> probs (coalesced via LDS), ----------
// ---------- pw via vwa-MFMA (incl rowsum row), selection softmax -> selp     ----------
__launch_bounds__(512, 4)
__global__ void k_attn2(const u16* __restrict__ qkvb, const u16* __restrict__ vwa,
                        u16* __restrict__ probs, float* __restrict__ selp, int bh0){
  __shared__ u16 Qs[64*64];     // 8 KB (XOR r&7 swizzle)
  __shared__ u16 Ks[128*64];    // 16 KB
  __shared__ u16 P[64*136];     // 17.4 KB (+8 pad)
  __shared__ float pwL[8][16][16];  // 8 KB
  const int tid = threadIdx.x, lane = tid & 63, wid = tid >> 6;
  const int bhl = blockIdx.y;
  const int bh = bh0 + bhl;
  const int t0 = blockIdx.x * 64;
  const int b = bh >> 4, h = bh & 15;
  const u16* qbase = qkvb + b*3072 + h*64;
  const u16* kbase = qkvb + b*3072 + 1024 + h*64;
  const u16* vwbase = vwa + (size_t)b*16*SS;
  u16* pbase = probs + ((size_t)bhl*TT + t0)*SS;
  const f32x4 fzero = {0.f, 0.f, 0.f, 0.f};

  { // stage Q 64x64 once
    int c = tid, r = c >> 3, sl = c & 7;
    gl_lds16(qbase + (size_t)(t0 + r)*6144 + 8*(sl ^ (r & 7)), &Qs[c*8]);
  }
  __syncthreads();
  bf16x8 qf[4][2];
  #pragma unroll
  for (int mt = 0; mt < 4; ++mt)
    #pragma unroll
    for (int kk = 0; kk < 2; ++kk){
      int r = mt*16 + (lane & 15);
      int pos = (kk*4 + (lane >> 4)) ^ (r & 7);
      qf[mt][kk] = *(const bf16x8*)&Qs[r*64 + pos*8];
    }

  f32x4 pwacc = fzero;
  const int mtp = wid & 3, kks = (wid >> 2)*2;   // pw split: wave -> (mt, kk-pair)

  for (int s0 = 0; s0 < SS; s0 += 128){
    #pragma unroll
    for (int it = 0; it < 2; ++it){
      int c = it*512 + tid, r = c >> 3, sl = c & 7;
      gl_lds16(kbase + (size_t)(s0 + r)*6144 + 8*(sl ^ (r & 7)), &Ks[c*8]);
    }
    __syncthreads();   // K staged; prev-iter P reads (pw/copy) already drained at this barrier
    bf16x8 kf[2];
    #pragma unroll
    for (int kk = 0; kk < 2; ++kk){
      int r = wid*16 + (lane & 15);
      int pos = (kk*4 + (lane >> 4)) ^ (r & 7);
      kf[kk] = *(const bf16x8*)&Ks[r*64 + pos*8];
    }
    // swapped S' = mfma(K, Q): lane holds t = bt*16+(lane&15); s = wid*16+(lane>>4)*4+j
    #pragma unroll
    for (int bt = 0; bt < 4; ++bt){
      f32x4 sa = fzero;
      sa = __builtin_amdgcn_mfma_f32_16x16x32_bf16(kf[0], qf[bt][0], sa, 0, 0, 0);
      sa = __builtin_amdgcn_mfma_f32_16x16x32_bf16(kf[1], qf[bt][1], sa, 0, 0, 0);
      u32 w0 = (u32)f2bf(__expf(sa[0])) | ((u32)f2bf(__expf(sa[1])) << 16);
      u32 w1 = (u32)f2bf(__expf(sa[2])) | ((u32)f2bf(__expf(sa[3])) << 16);
      int t = bt*16 + (lane & 15);
      int sl = wid*16 + (lane >> 4)*4;
      uint2 pk; pk.x = w0; pk.y = w1;
      *(uint2*)&P[t*136 + sl] = pk;
    }
    __syncthreads();   // P complete
    bf16x8 vwf[2];
    #pragma unroll
    for (int kq = 0; kq < 2; ++kq)
      vwf[kq] = *(const bf16x8*)&vwbase[(size_t)(lane & 15)*SS + s0 + (kks + kq)*32 + (lane >> 4)*8];
    #pragma unroll
    for (int kq = 0; kq < 2; ++kq){
      int kk = kks + kq;
      bf16x8 pa = *(const bf16x8*)&P[(mtp*16 + (lane & 15))*136 + kk*32 + (lane >> 4)*8];
      pwacc = __builtin_amdgcn_mfma_f32_16x16x32_bf16(pa, vwf[kq], pwacc, 0, 0, 0);
    }
    // coalesced copy P tile (64x128) to global: 256B contiguous per row
    #pragma unroll
    for (int cc = 0; cc < 2; ++cc){
      int c = cc*512 + tid;          // 1024 chunks of 8 elems
      int row = c >> 4, col = c & 15;
      bf16x8 v = *(const bf16x8*)&P[row*136 + col*8];
      *(bf16x8*)&pbase[(size_t)row*SS + s0 + col*8] = v;
    }
  }

  // selection: combine pw halves, softmax over rules, selp = sel/rowsum
  #pragma unroll
  for (int j = 0; j < 4; ++j)
    pwL[wid][(lane >> 4)*4 + j][lane & 15] = pwacc[j];
  __syncthreads();
  if (tid < 64){
    int mt = tid >> 4, tr = tid & 15;
    float pw[9];
    #pragma unroll
    for (int r = 0; r < 9; ++r) pw[r] = pwL[mt][tr][r] + pwL[mt + 4][tr][r];
    float rs = pw[8];
    float inv = 1.0f / rs;
    float mx = -3.0e38f;
    #pragma unroll
    for (int r = 0; r < 8; ++r) mx = fmaxf(mx, pw[r]*inv);
    float e[8], ssum = 0.f;
    #pragma unroll
    for (int r = 0; r < 8; ++r){ e[r] = __expf(pw[r]*inv - mx); ssum += e[r]; }
    #pragma unroll
    for (int r = 0; r < 8; ++r)
      selp[((size_t)bh*TT + t0 + tid)*8 + r] = e[r] / (ssum * rs);
  }
}

// ---------- k_pv6: 256x256 tile, m201-style 8-phase schedule (4 phases x 2 kk per K-tile) ----
// ROUNDS 6/9/10/11: 1-barrier-per-K-step structure plateaus at 43-45% MfmaUtil (~1000 TF).
// m201's lever (per m196 A/B) is the fine per-phase interleave itself. Port:
//   LDS: 2 buffers x 1 K-tile (BK=64): A[2 subk][256][32] + B[2 subk][256][32] = 64 KB/buf.
//   Per K-tile kt: 4 phases (kk, N-half): {ds_read 10/2/10/2; stage 1 half-tile of kt+1
//   into buf[kt&1^1]; barrier; setprio; 16 MFMA; setprio; barrier}.
//   Counted vmcnt LEDGER (2 glds/thread/stage, uniform): consumption of subk_s of kt needs
//   stages issued 8 loads ago -> vmcnt(4) at p1-end and p3-end lands exactly the next two
//   phases' data; 4 loads always in flight (never drains). Tail kt=31: no stages, mid
//   vmcnt(0). Prologue: 4 half-stages + vmcnt(4).
// Swizzle per 32-elem subk row = pv4's proven conflict-free pattern. Epilogue = pv4's.
__launch_bounds__(512, 2)
__global__ void k_pv6(const u16* __restrict__ probs, const u16* __restrict__ Vt2,
                      const float* __restrict__ selp, u16* __restrict__ oattn,
                      int bh0, int G){
  __shared__ u16 L[2*32768];   // 2 bufs x 64 KB: [A subk0|A subk1|B subk0|B subk1] x 16 KB
  const int tid = threadIdx.x, lane = tid & 63, wid = tid >> 6;
  const int mw = wid & 1, nw2 = wid >> 1;   // 2 M-waves x 4 N-waves
  int fid = blockIdx.x, bhl, xy;
  if (G >= 8){ bhl = (fid & 7) + 8*(fid >> 8); xy = (fid >> 3) & 31; }
  else       { bhl = fid >> 5;                 xy = fid & 31; }
  const int t0 = (xy >> 2) * 256;
  const int n0 = (xy & 3) * 256;
  const int bh = bh0 + bhl, b = bh >> 4, h = bh & 15;
  const u16* Abase = probs + ((size_t)bhl*TT + t0)*SS;
  const u16* Bbase = Vt2 + (size_t)b*1024*SS + (size_t)n0*SS;
  const f32x4 fzero = {0.f, 0.f, 0.f, 0.f};
  f32x4 acc[8][4];
  #pragma unroll
  for (int a = 0; a < 8; ++a)
    #pragma unroll
    for (int c = 0; c < 4; ++c) acc[a][c] = fzero;

  // stage half-tile `which` of K-tile kt: 0=A.subk0 1=B.subk0 2=A.subk1 3=B.subk1
  auto stageH = [&](int kt, int which){
    int isB = which & 1, subk = which >> 1;
    u16* dst = &L[(kt & 1)*32768 + isB*16384 + subk*8192];
    const u16* src = isB ? Bbase : Abase;
    #pragma unroll
    for (int i = 0; i < 2; ++i){
      int ci = i*512 + tid, r = ci >> 2, sl = ci & 3;   // 1024 chunks: 256 rows x 4 slots
      gl_lds16(src + (size_t)r*SS + kt*64 + subk*32 + 8*(sl ^ ((r >> 1) & 3)), &dst[ci*8]);
    }
  };
  auto readA = [&](int kt, int kk, bf16x8 (&af)[8]){
    const u16* As = &L[(kt & 1)*32768 + kk*8192];
    #pragma unroll
    for (int mf = 0; mf < 8; ++mf){
      int r = mw*128 + mf*16 + (lane & 15);
      int pos = (lane >> 4) ^ ((r >> 1) & 3);
      af[mf] = *(const bf16x8*)&As[r*32 + pos*8];
    }
  };
  auto readB = [&](int kt, int kk, int nh, bf16x8 (&bfr)[2]){
    const u16* Bs = &L[(kt & 1)*32768 + 16384 + kk*8192];
    #pragma unroll
    for (int nf = 0; nf < 2; ++nf){
      int r = nw2*64 + nh*32 + nf*16 + (lane & 15);
      int pos = (lane >> 4) ^ ((r >> 1) & 3);
      bfr[nf] = *(const bf16x8*)&Bs[r*32 + pos*8];
    }
  };
  auto mfma16 = [&](bf16x8 (&af)[8], bf16x8 (&bfr)[2], int nh){
    __builtin_amdgcn_s_setprio(1);
    #pragma unroll
    for (int mf = 0; mf < 8; ++mf)
      #pragma unroll
      for (int nf = 0; nf < 2; ++nf)
        acc[mf][nh*2 + nf] = __builtin_amdgcn_mfma_f32_16x16x32_bf16(af[mf], bfr[nf], acc[mf][nh*2 + nf], 0, 0, 0);
    __builtin_amdgcn_s_setprio(0);
  };

  // prologue: stage K-tile 0 (4 halves = 8 loads); subk0 must land, subk1 stays in flight
  stageH(0, 0); stageH(0, 1); stageH(0, 2); stageH(0, 3);
  asm volatile("s_waitcnt vmcnt(4)" ::: "memory");
  __builtin_amdgcn_s_barrier();
  __builtin_amdgcn_sched_barrier(0);

  bf16x8 af[8], bfr[2];
  for (int kt = 0; kt < 32; ++kt){
    const bool last = (kt == 31);
    // ---- p0: kk0, N0 ----
    readA(kt, 0, af);
    readB(kt, 0, 0, bfr);
    if (!last) stageH(kt + 1, 0);
    __builtin_amdgcn_s_barrier();
    mfma16(af, bfr, 0);
    __builtin_amdgcn_s_barrier();
    // ---- p1: kk0, N1 (reuse af) ----
    readB(kt, 0, 1, bfr);
    if (!last) stageH(kt + 1, 1);
    __builtin_amdgcn_s_barrier();
    mfma16(af, bfr, 1);
    if (!last) asm volatile("s_waitcnt vmcnt(4)" ::: "memory");  // subk1 of kt landed
    else       asm volatile("s_waitcnt vmcnt(0)" ::: "memory");
    __builtin_amdgcn_s_barrier();
    __builtin_amdgcn_sched_barrier(0);
    // ---- p2: kk1, N0 ----
    readA(kt, 1, af);
    readB(kt, 1, 0, bfr);
    if (!last) stageH(kt + 1, 2);
    __builtin_amdgcn_s_barrier();
    mfma16(af, bfr, 0);
    __builtin_amdgcn_s_barrier();
    // ---- p3: kk1, N1 (reuse af) ----
    readB(kt, 1, 1, bfr);
    if (!last) stageH(kt + 1, 3);
    __builtin_amdgcn_s_barrier();
    mfma16(af, bfr, 1);
    asm volatile("s_waitcnt vmcnt(%0)" :: "i"(4) : "memory");    // subk0 of kt+1 landed
    __builtin_amdgcn_s_barrier();
    __builtin_amdgcn_sched_barrier(0);
  }

  // register epilogue: col = n0 + nw2*64 + nfg*16 + c15; rule = c15&7; d = col>>3.
  const int c15 = lane & 15, g = lane >> 4, r8 = c15 & 7;
  float sel[8][4];
  #pragma unroll
  for (int mf = 0; mf < 8; ++mf)
    #pragma unroll
    for (int j = 0; j < 4; ++j){
      int trow = t0 + mw*128 + mf*16 + g*4 + j;
      sel[mf][j] = selp[((size_t)bh*TT + trow)*8 + r8];
    }
  #pragma unroll
  for (int mf = 0; mf < 8; ++mf)
    #pragma unroll
    for (int nf = 0; nf < 4; ++nf){
      float v0 = acc[mf][nf][0] * sel[mf][0];
      float v1 = acc[mf][nf][1] * sel[mf][1];
      float v2 = acc[mf][nf][2] * sel[mf][2];
      float v3 = acc[mf][nf][3] * sel[mf][3];
      #pragma unroll
      for (int mask = 1; mask < 8; mask <<= 1){
        v0 += __shfl_xor(v0, mask, 64);
        v1 += __shfl_xor(v1, mask, 64);
        v2 += __shfl_xor(v2, mask, 64);
        v3 += __shfl_xor(v3, mask, 64);
      }
      if (r8 == 0){
        int dglob = (n0 >> 3) + nw2*8 + nf*2 + (c15 >> 3);
        int tb = t0 + mw*128 + mf*16 + g*4;
        u16* dst = oattn + (size_t)(tb*BB + b)*2048 + h*128 + dglob;
        dst[0*BB*2048] = f2bf(v0);
        dst[1*BB*2048] = f2bf(v1);
        dst[2*BB*2048] = f2bf(v2);
        dst[3*BB*2048] = f2bf(v3);
      }
    }
}

// ------------------------------------------------------------------
extern "C" void kernel_launch(void* const* d_in, const int* in_sizes, int n_in,
                              void* d_out, int out_size, void* d_ws, size_t ws_size,
                              hipStream_t stream){
  (void)in_sizes; (void)n_in;
  const float* query = (const float*)d_in[0];
  const float* Wq  = (const float*)d_in[1];
  const float* bq  = (const float*)d_in[2];
  const float* Wk  = (const float*)d_in[3];
  const float* bk  = (const float*)d_in[4];
  const float* Wv  = (const float*)d_in[5];
  const float* bv  = (const float*)d_in[6];
  // d_in[7] Wvq, d_in[8] bvq, d_in[10] bsc: provably unused (softmax_r shift-invariance)
  const float* Wsc = (const float*)d_in[9];
  const float* Wo  = (const float*)d_in[11];
  const float* bo  = (const float*)d_in[12];

  char* p = (char*)d_ws;
  auto carve = [&](size_t bytes) -> char* {
    char* r = p; p += (bytes + 255) & ~((size_t)255); return r;
  };
  u16*   Xb     = (u16*)  carve((size_t)MROWS*1024*2);     // query bf16          8.4 MB
  u16*   Wb     = (u16*)  carve((size_t)3072*1024*2);      // [Wq*.125|Wk|Wv]     6.3 MB
  u16*   Wob    = (u16*)  carve((size_t)1024*2048*2);      // Wo bf16             4.2 MB
  float* bb     = (float*)carve(3072*4);
  u16*   qkvb   = (u16*)  carve((size_t)MROWS*3072*2);     // [q|k|v] bf16       25.2 MB
  u16*   Vt2    = (u16*)  carve((size_t)BB*1024*SS*2);     // V^T rule-interleaved 8.4 MB
  u16*   vwa    = (u16*)  carve((size_t)BB*16*SS*2);       // vw_aug              0.13 MB
  u16*   oattn  = (u16*)  carve((size_t)MROWS*2048*2);     // attn out bf16      16.8 MB
  float* selp   = (float*)carve((size_t)32*TT*RR*4);       // sel/rowsum          2.1 MB
  size_t fixed = (size_t)(p - (char*)d_ws);
  int G = 32;                                               // bh per chunk (probs = G*8.4MB)
  while (G > 1 && fixed + ((size_t)G*TT*SS*2 + 256) > ws_size) G >>= 1;
  u16* probs;
  if (fixed + ((size_t)G*TT*SS*2 + 256) <= ws_size){
    probs = (u16*)carve((size_t)G*TT*SS*2);
  } else {
    // ws too small even for G=1: overlay probs on Xb (8.39 MB each; Xb is dead
    // after the qkv GEMM and is re-created by k_cvt on every graph replay)
    G = 1;
    probs = Xb;
  }

  k_cvt<<<1024, 256, 0, stream>>>(query, Xb, MROWS*1024, 1.0f);
  k_cvt<<<512, 256, 0, stream>>>(Wq, Wb, 1024*1024, 0.125f);
  k_cvt<<<512, 256, 0, stream>>>(Wk, Wb + 1024*1024, 1024*1024, 1.0f);
  k_cvt<<<512, 256, 0, stream>>>(Wv, Wb + 2*1024*1024, 1024*1024, 1.0f);
  k_cvt<<<1024, 256, 0, stream>>>(Wo, Wob, 1024*2048, 1.0f);
  k_bias<<<4, 256, 0, stream>>>(bq, bk, bv, bb);
  k_gemm<1024, true><<<dim3(24, 32), 256, 0, stream>>>(Xb, Wb, bb, qkvb, 3072);
  k_transpose<<<dim3(64, 32, 2), 256, 0, stream>>>(qkvb, Vt2);
  k_vw2<<<256, 256, 0, stream>>>(qkvb, Wsc, vwa);
  for (int bh0 = 0; bh0 < 32; bh0 += G){
    k_attn2<<<dim3(32, G), 512, 0, stream>>>(qkvb, vwa, probs, selp, bh0);
    k_pv6<<<G*32, 512, 0, stream>>>(probs, Vt2, selp, oattn, bh0, G);
  }
  k_gemm<2048, false><<<dim3(8, 32), 256, 0, stream>>>(oattn, Wob, bo, d_out, 1024);
}